// Round 1
// baseline (46386.346 us; speedup 1.0000x reference)
//
#include <hip/hip_runtime.h>
#include <cstdint>

// ---------------- problem dims ----------------
#define TB 8
#define TS 128
#define TDIN 768
#define TN 64
#define TD 128
#define TH 4
#define TDH 32
#define TMAXT 8
#define SLOT_PAD 132   // 64x132 fp32 slot tile: keeps ds_read_b128 bank-even and 16B-aligned

// ---------------- workspace layout (float offsets) ----------------
#define WS_WLAM 0                         // 128*128 : diag(lam) @ dn_wo
#define WS_M    16384                     // 128*128 : M = w_q @ w_k^T  (qk = xp @ M)
#define WS_QK   32768                     // B*S*128 : per-(b,s) query-key vector
#define WS_ACC  (32768 + 131072)          // B*S*128 : per-step acc (consumed by epilogue)
#define WS_HALT (163840 + 131072)         // u64[MAXT*8]: packed {stamp<<32 | halt bits}

__device__ __forceinline__ float wsum64(float v) {
  v += __shfl_xor(v, 1);  v += __shfl_xor(v, 2);  v += __shfl_xor(v, 4);
  v += __shfl_xor(v, 8);  v += __shfl_xor(v, 16); v += __shfl_xor(v, 32);
  return v;
}
__device__ __forceinline__ float wmax64(float v) {
  v = fmaxf(v, __shfl_xor(v, 1));  v = fmaxf(v, __shfl_xor(v, 2));
  v = fmaxf(v, __shfl_xor(v, 4));  v = fmaxf(v, __shfl_xor(v, 8));
  v = fmaxf(v, __shfl_xor(v, 16)); v = fmaxf(v, __shfl_xor(v, 32));
  return v;
}

// ================= kernel 0: Wlam and M = w_q @ w_k^T =================
__global__ __launch_bounds__(256) void k0_prep(const float* __restrict__ w_q,
                                               const float* __restrict__ w_k,
                                               const float* __restrict__ dn_lam,
                                               const float* __restrict__ dn_wo,
                                               float* __restrict__ ws) {
  const int bx = blockIdx.x, tid = threadIdx.x;
  if (bx < 32) {
    int i = bx * 512 + tid;
    ws[WS_WLAM + i] = dn_lam[i >> 7] * dn_wo[i];
    i += 256;
    ws[WS_WLAM + i] = dn_lam[i >> 7] * dn_wo[i];
  } else {
    __shared__ float part[2][128];
    const int r0 = (bx - 32) * 4;
    const int c = tid & 127, half = tid >> 7;
    for (int rr = 0; rr < 4; ++rr) {
      const int k = r0 + rr;
      const float* wq = w_q + k * TD + half * 64;
      const float* wk = w_k + c * TD + half * 64;
      float p = 0.f;
      #pragma unroll 8
      for (int d = 0; d < 64; ++d) p = fmaf(wq[d], wk[d], p);
      part[half][c] = p;
      __syncthreads();
      if (tid < 128) ws[WS_M + k * TD + tid] = part[0][tid] + part[1][tid];
      __syncthreads();
    }
  }
}

// ================= kernel 1: qk_all[b][s] = LN(x) @ w_in @ M =================
__global__ __launch_bounds__(256) void k1_qk(const float* __restrict__ x,
                                             const float* __restrict__ ln_w,
                                             const float* __restrict__ ln_b,
                                             const float* __restrict__ w_in,
                                             float* __restrict__ ws) {
  const int bx = blockIdx.x, tid = threadIdx.x;
  const int b = bx >> 5;             // 8 batches x 32 blocks
  const int s0 = (bx & 31) * 4;      // 4 seq positions per block
  const int wv = tid >> 6, lane = tid & 63;

  __shared__ float xn[4][TDIN];
  __shared__ float xp[4][TD];
  __shared__ float part[2][4][TD];
  __shared__ float red[4];

  for (int ss = 0; ss < 4; ++ss) {
    const float* xrow = x + ((size_t)(b * TS + s0 + ss)) * TDIN;
    float v0 = xrow[tid], v1 = xrow[tid + 256], v2 = xrow[tid + 512];
    float p = wsum64(v0 + v1 + v2);
    if (lane == 0) red[wv] = p;
    __syncthreads();
    const float mu = (red[0] + red[1] + red[2] + red[3]) * (1.f / 768.f);
    __syncthreads();
    const float d0 = v0 - mu, d1 = v1 - mu, d2 = v2 - mu;
    p = wsum64(d0 * d0 + d1 * d1 + d2 * d2);
    if (lane == 0) red[wv] = p;
    __syncthreads();
    const float var = (red[0] + red[1] + red[2] + red[3]) * (1.f / 768.f);
    const float rstd = 1.f / sqrtf(var + 1e-5f);
    xn[ss][tid]       = d0 * rstd * ln_w[tid]       + ln_b[tid];
    xn[ss][tid + 256] = d1 * rstd * ln_w[tid + 256] + ln_b[tid + 256];
    xn[ss][tid + 512] = d2 * rstd * ln_w[tid + 512] + ln_b[tid + 512];
    __syncthreads();
  }

  // x_proj = xn @ w_in   (coalesced: lanes over output dim d)
  {
    const int d = tid & 127, j = tid >> 7;    // j in 0..1, 384 k each
    float a0 = 0.f, a1 = 0.f, a2 = 0.f, a3 = 0.f;
    const int kb = j * 384;
    #pragma unroll 4
    for (int k = 0; k < 384; ++k) {
      const float w = w_in[(kb + k) * TD + d];
      a0 = fmaf(xn[0][kb + k], w, a0);
      a1 = fmaf(xn[1][kb + k], w, a1);
      a2 = fmaf(xn[2][kb + k], w, a2);
      a3 = fmaf(xn[3][kb + k], w, a3);
    }
    part[j][0][d] = a0; part[j][1][d] = a1; part[j][2][d] = a2; part[j][3][d] = a3;
  }
  __syncthreads();
  if (tid < 128) {
    #pragma unroll
    for (int ss = 0; ss < 4; ++ss) xp[ss][tid] = part[0][ss][tid] + part[1][ss][tid];
  }
  __syncthreads();
  // qk = xp @ M
  {
    const int c = tid & 127, j = tid >> 7;
    float a0 = 0.f, a1 = 0.f, a2 = 0.f, a3 = 0.f;
    const float* Mp = ws + WS_M;
    const int kb = j * 64;
    #pragma unroll 4
    for (int k = 0; k < 64; ++k) {
      const float m = Mp[(kb + k) * TD + c];
      a0 = fmaf(xp[0][kb + k], m, a0);
      a1 = fmaf(xp[1][kb + k], m, a1);
      a2 = fmaf(xp[2][kb + k], m, a2);
      a3 = fmaf(xp[3][kb + k], m, a3);
    }
    part[j][0][c] = a0; part[j][1][c] = a1; part[j][2][c] = a2; part[j][3][c] = a3;
  }
  __syncthreads();
  if (tid < 128) {
    #pragma unroll
    for (int ss = 0; ss < 4; ++ss)
      ws[WS_QK + (size_t)(b * TS + s0 + ss) * TD + tid] = part[0][ss][tid] + part[1][ss][tid];
  }
}

// ================= kernel 2: the recurrence (8 persistent blocks, 1 per batch) =================
__global__ __launch_bounds__(1024) void k2_main(
    const float* __restrict__ slot_memory,
    const float* __restrict__ w_v,     const float* __restrict__ w_gate,  const float* __restrict__ b_gate,
    const float* __restrict__ halt_w1, const float* __restrict__ halt_b1,
    const float* __restrict__ halt_w2, const float* __restrict__ halt_b2,
    const float* __restrict__ dn_wk,   const float* __restrict__ dn_wv,
    const float* __restrict__ dn_wb,   const float* __restrict__ dn_bb,
    const float* __restrict__ dn_wo,
    float* __restrict__ ws, float* __restrict__ out) {
  const int tid = threadIdx.x;
  const int b = blockIdx.x;
  const int lane = tid & 63, wv = tid >> 6;

  __shared__ float sh_slots[TN * SLOT_PAD];
  __shared__ float sh_scores[TN];
  __shared__ float sh_attn[TN];
  __shared__ float sh_rspart[8][TD];
  __shared__ float sh_rs[TD];
  __shared__ float sh_ropart[8][TD];
  __shared__ float sh_ro[TD];
  __shared__ float sh_hpart[4][TN];
  __shared__ float sh_gpart[4][TN];
  __shared__ float sh_kpart[2][TD];
  __shared__ float sh_vpart[2][TD];
  __shared__ float sh_bpart[8][TH];
  __shared__ float sh_gate[TN];
  __shared__ float sh_kn[TD];
  __shared__ float sh_v[TD];
  __shared__ float sh_beta[TH];
  __shared__ float sh_vo[TH][TD];
  __shared__ float sh_ko[TH][TD];
  __shared__ float sh_kh[TN][TH];
  __shared__ float sh_acc[TD];
  __shared__ float sh_qk[TD];
  __shared__ float sh_misc[16];

  unsigned long long* hslots = (unsigned long long*)(ws + WS_HALT);
  const float* Wlam = ws + WS_WLAM;

  // init slots (broadcast of slot_memory over batch)
  for (int i = tid; i < TN * TD; i += 1024)
    sh_slots[(i >> 7) * SLOT_PAD + (i & 127)] = slot_memory[i];
  __syncthreads();

  float G[8];  // G = slots @ Wlam, this thread's tile: row=lane, cols=8*wv..8*wv+8
  auto do_gemm = [&]() {
    #pragma unroll
    for (int j = 0; j < 8; ++j) G[j] = 0.f;
    const float* srow = sh_slots + lane * SLOT_PAD;
    const float* wc = Wlam + wv * 8;
    for (int k0 = 0; k0 < TD; k0 += 4) {
      const float4 sv = *(const float4*)(srow + k0);
      const float* svp = reinterpret_cast<const float*>(&sv);
      #pragma unroll
      for (int kk = 0; kk < 4; ++kk) {
        const float a = svp[kk];
        const float4 w0 = *(const float4*)(wc + (k0 + kk) * TD);
        const float4 w1 = *(const float4*)(wc + (k0 + kk) * TD + 4);
        G[0] = fmaf(a, w0.x, G[0]); G[1] = fmaf(a, w0.y, G[1]);
        G[2] = fmaf(a, w0.z, G[2]); G[3] = fmaf(a, w0.w, G[3]);
        G[4] = fmaf(a, w1.x, G[4]); G[5] = fmaf(a, w1.y, G[5]);
        G[6] = fmaf(a, w1.z, G[6]); G[7] = fmaf(a, w1.w, G[7]);
      }
    }
  };
  do_gemm();

  const float scale = sqrtf((float)TD);

  for (int s = 0; s < TS; ++s) {
    if (tid < TD) { sh_qk[tid] = ws[WS_QK + (size_t)(b * TS + s) * TD + tid]; sh_acc[tid] = 0.f; }
    __syncthreads();
    float rem = 1.f;  // replicated per thread, updated identically

    for (int t = 0; t < TMAXT; ++t) {
      if (t >= 2) {
        // consume halts(t-1) of all batches; break if mean > THR (t-1 > 0 holds)
        if (tid < 8) {
          const unsigned long long want = (unsigned long long)(unsigned)(s * 8 + (t - 1));
          unsigned long long vv_;
          do {
            vv_ = __hip_atomic_load(&hslots[(t - 1) * 8 + tid], __ATOMIC_RELAXED, __HIP_MEMORY_SCOPE_AGENT);
          } while ((vv_ >> 32) != want);
          float hv = __uint_as_float((unsigned)vv_);
          hv += __shfl_xor(hv, 1); hv += __shfl_xor(hv, 2); hv += __shfl_xor(hv, 4);
          if (tid == 0) sh_misc[2] = hv * 0.125f;
        }
        __syncthreads();
        if (sh_misc[2] > 0.5f) break;
      }

      // A: scores_n = slots_n . qk
      {
        const int n = tid >> 4, j = tid & 15;
        const float* srow = sh_slots + n * SLOT_PAD + j * 8;
        const float* qp = sh_qk + j * 8;
        float p = 0.f;
        #pragma unroll
        for (int i = 0; i < 8; ++i) p = fmaf(srow[i], qp[i], p);
        p += __shfl_xor(p, 1); p += __shfl_xor(p, 2); p += __shfl_xor(p, 4); p += __shfl_xor(p, 8);
        if (j == 0) sh_scores[n] = p;
      }
      __syncthreads();
      // B: softmax over n (wave 0)
      if (wv == 0) {
        const float y = sh_scores[lane] / scale;
        const float m = wmax64(y);
        const float p = expf(y - m);
        const float sm = wsum64(p);
        sh_attn[lane] = p / sm;
      }
      __syncthreads();
      // C: rs = sum_n attn_n * slots_n  (partials)
      {
        const int d = tid & 127, j = tid >> 7;
        float p = 0.f;
        #pragma unroll
        for (int i = 0; i < 8; ++i)
          p = fmaf(sh_attn[j * 8 + i], sh_slots[(j * 8 + i) * SLOT_PAD + d], p);
        sh_rspart[j][d] = p;
      }
      __syncthreads();
      // D: rs final
      if (tid < TD) {
        float p = 0.f;
        #pragma unroll
        for (int j = 0; j < 8; ++j) p += sh_rspart[j][tid];
        sh_rs[tid] = p;
      }
      __syncthreads();
      // E: read_out = rs @ w_v (partials, coalesced over d)
      {
        const int d = tid & 127, j = tid >> 7;
        const float* wp = w_v + (j * 16) * TD + d;
        const float* rp = sh_rs + j * 16;
        float p = 0.f;
        #pragma unroll
        for (int i = 0; i < 16; ++i) p = fmaf(rp[i], wp[i * TD], p);
        sh_ropart[j][d] = p;
      }
      __syncthreads();
      // F: read_out final
      if (tid < TD) {
        float p = 0.f;
        #pragma unroll
        for (int j = 0; j < 8; ++j) p += sh_ropart[j][tid];
        sh_ro[tid] = p;
      }
      __syncthreads();
      // G: all consumers of read_out (partials)
      if (tid < 256) {
        const int g = tid & 63, j = (tid >> 6) & 3;
        const float* wp = halt_w1 + (j * 32) * TN + g;
        const float* rp = sh_ro + j * 32;
        float p = 0.f;
        #pragma unroll 8
        for (int i = 0; i < 32; ++i) p = fmaf(rp[i], wp[i * TN], p);
        sh_hpart[j][g] = p;
        if (tid < 32) {
          const int h = tid & 3, jj = tid >> 2;
          const float* wb = dn_wb + (jj * 16) * TH + h;
          const float* rb = sh_ro + jj * 16;
          float pb = 0.f;
          #pragma unroll
          for (int i = 0; i < 16; ++i) pb = fmaf(rb[i], wb[i * TH], pb);
          sh_bpart[jj][h] = pb;
        }
      } else if (tid < 512) {
        const int t2 = tid - 256, g = t2 & 63, j = t2 >> 6;
        const float* wp = w_gate + (j * 32) * TN + g;
        const float* rp = sh_ro + j * 32;
        float p = 0.f;
        #pragma unroll 8
        for (int i = 0; i < 32; ++i) p = fmaf(rp[i], wp[i * TN], p);
        sh_gpart[j][g] = p;
      } else if (tid < 768) {
        const int t2 = tid - 512, d = t2 & 127, j = t2 >> 7;
        const float* wp = dn_wk + (j * 64) * TD + d;
        const float* rp = sh_ro + j * 64;
        float p = 0.f;
        #pragma unroll 8
        for (int i = 0; i < 64; ++i) p = fmaf(rp[i], wp[i * TD], p);
        sh_kpart[j][d] = p;
      } else {
        const int t2 = tid - 768, d = t2 & 127, j = t2 >> 7;
        const float* wp = dn_wv + (j * 64) * TD + d;
        const float* rp = sh_ro + j * 64;
        float p = 0.f;
        #pragma unroll 8
        for (int i = 0; i < 64; ++i) p = fmaf(rp[i], wp[i * TD], p);
        sh_vpart[j][d] = p;
      }
      __syncthreads();
      // H: finals (halt/gate/kraw+norm/v/beta), halt publish
      if (wv == 0) {
        float tt = sh_hpart[0][lane] + sh_hpart[1][lane] + sh_hpart[2][lane] + sh_hpart[3][lane] + halt_b1[lane];
        tt = fmaxf(tt, 0.f);
        const float z = wsum64(tt * halt_w2[lane]);
        if (lane == 0) {
          const float hl = 1.f / (1.f + expf(-(z + halt_b2[0])));
          sh_misc[3] = hl;
          if (t >= 1 && t <= 6) {
            const unsigned long long pv =
                ((unsigned long long)(unsigned)(s * 8 + t) << 32) | (unsigned long long)__float_as_uint(hl);
            __hip_atomic_store(&hslots[t * 8 + b], pv, __ATOMIC_RELAXED, __HIP_MEMORY_SCOPE_AGENT);
          }
        }
      } else if (wv == 1) {
        const float gg = sh_gpart[0][lane] + sh_gpart[1][lane] + sh_gpart[2][lane] + sh_gpart[3][lane] + b_gate[lane];
        sh_gate[lane] = 1.f / (1.f + expf(-gg));
      } else if (wv == 2 || wv == 3) {
        const int d = tid - 128;
        const float kr = sh_kpart[0][d] + sh_kpart[1][d];
        sh_kn[d] = kr;
        float sq = kr * kr;
        sq += __shfl_xor(sq, 1); sq += __shfl_xor(sq, 2); sq += __shfl_xor(sq, 4);
        sq += __shfl_xor(sq, 8); sq += __shfl_xor(sq, 16);
        if ((lane & 31) == 0) sh_misc[8 + (d >> 5)] = sq;
      } else if (wv == 4 || wv == 5) {
        const int d = tid - 256;
        sh_v[d] = sh_vpart[0][d] + sh_vpart[1][d];
      } else if (wv == 6 && lane < 4) {
        float bs = dn_bb[lane];
        #pragma unroll
        for (int jj = 0; jj < 8; ++jj) bs += sh_bpart[jj][lane];
        sh_beta[lane] = 2.f / (1.f + expf(-bs));
      }
      __syncthreads();
      // I: normalize k per head
      if (tid < TD) {
        const int h = tid >> 5;
        sh_kn[tid] = sh_kn[tid] / (sqrtf(sh_misc[8 + h]) + 1e-6f);
      }
      __syncthreads();
      // J: Vo/Ko per head, kh per slot
      if (tid < 512) {
        const int h = tid >> 7, d = tid & 127;
        const float* wop = dn_wo + (h * 32) * TD + d;
        const float* vp = sh_v + h * 32;
        float p = 0.f;
        #pragma unroll 8
        for (int i = 0; i < 32; ++i) p = fmaf(vp[i], wop[i * TD], p);
        sh_vo[h][d] = sh_beta[h] * p;
        if (tid < 256) {
          const int n = tid >> 2, hh = tid & 3;
          const float* kp = sh_kn + hh * 32;
          const float* sp = sh_slots + n * SLOT_PAD + hh * 32;
          float pk = 0.f;
          #pragma unroll 8
          for (int i = 0; i < 32; ++i) pk = fmaf(kp[i], sp[i], pk);
          sh_kh[n][hh] = pk;
        }
      } else {
        const int t2 = tid - 512, h = t2 >> 7, d = t2 & 127;
        const float* wop = dn_wo + (h * 32) * TD + d;
        const float* kp = sh_kn + h * 32;
        float p = 0.f;
        #pragma unroll 8
        for (int i = 0; i < 32; ++i) p = fmaf(kp[i], wop[i * TD], p);
        sh_ko[h][d] = sh_beta[h] * p;
      }
      __syncthreads();
      // K: acc/rem update + slot apply
      {
        const float hl = sh_misc[3];
        if (tid < TD) sh_acc[tid] += rem * sh_ro[tid];
        const float g = sh_gate[lane];
        float u[8];
        #pragma unroll
        for (int j = 0; j < 8; ++j) u[j] = G[j];
        #pragma unroll
        for (int h = 0; h < TH; ++h) {
          const float khh = sh_kh[lane][h];
          const float4 va = *(const float4*)(&sh_vo[h][wv * 8]);
          const float4 vb = *(const float4*)(&sh_vo[h][wv * 8 + 4]);
          const float4 ka = *(const float4*)(&sh_ko[h][wv * 8]);
          const float4 kb = *(const float4*)(&sh_ko[h][wv * 8 + 4]);
          u[0] += va.x - khh * ka.x; u[1] += va.y - khh * ka.y;
          u[2] += va.z - khh * ka.z; u[3] += va.w - khh * ka.w;
          u[4] += vb.x - khh * kb.x; u[5] += vb.y - khh * kb.y;
          u[6] += vb.z - khh * kb.z; u[7] += vb.w - khh * kb.w;
        }
        float* srow = sh_slots + lane * SLOT_PAD + wv * 8;
        const float4 s0 = *(const float4*)(srow);
        const float4 s1 = *(const float4*)(srow + 4);
        const float* s0p = reinterpret_cast<const float*>(&s0);
        const float* s1p = reinterpret_cast<const float*>(&s1);
        float ns[8];
        #pragma unroll
        for (int j = 0; j < 8; ++j) {
          const float sj = (j < 4) ? s0p[j] : s1p[j - 4];
          ns[j] = (1.f - g) * sj + g * u[j];
        }
        *(float4*)(srow)     = make_float4(ns[0], ns[1], ns[2], ns[3]);
        *(float4*)(srow + 4) = make_float4(ns[4], ns[5], ns[6], ns[7]);
        if (t < TMAXT - 1) rem = rem * (1.f - hl);
      }
      __syncthreads();
      // L: G for the (possibly) next tick / next step
      do_gemm();
    }  // ticks

    if (tid < TD) ws[WS_ACC + (size_t)(b * TS + s) * TD + tid] = sh_acc[tid];
    __syncthreads();
  }  // steps

  // slots_final -> out
  for (int i = tid; i < TN * TD; i += 1024)
    out[(size_t)TB * TS * TDIN + (size_t)b * TN * TD + i] = sh_slots[(i >> 7) * SLOT_PAD + (i & 127)];
}

// ================= kernel 3: outs = acc_all @ w_out =================
__global__ __launch_bounds__(256) void k3_out(const float* __restrict__ w_out,
                                              const float* __restrict__ ws,
                                              float* __restrict__ out) {
  const int bx = blockIdx.x, tid = threadIdx.x;
  const int r0 = bx * 8;
  __shared__ float a8[8][TD];
  for (int i = tid; i < 8 * TD; i += 256)
    a8[i >> 7][i & 127] = ws[WS_ACC + (size_t)r0 * TD + i];
  __syncthreads();
  float p[8][3];
  #pragma unroll
  for (int ss = 0; ss < 8; ++ss) { p[ss][0] = 0.f; p[ss][1] = 0.f; p[ss][2] = 0.f; }
  #pragma unroll 2
  for (int d = 0; d < TD; ++d) {
    const float w0 = w_out[d * TDIN + tid];
    const float w1 = w_out[d * TDIN + tid + 256];
    const float w2 = w_out[d * TDIN + tid + 512];
    #pragma unroll
    for (int ss = 0; ss < 8; ++ss) {
      const float a = a8[ss][d];
      p[ss][0] = fmaf(a, w0, p[ss][0]);
      p[ss][1] = fmaf(a, w1, p[ss][1]);
      p[ss][2] = fmaf(a, w2, p[ss][2]);
    }
  }
  #pragma unroll
  for (int ss = 0; ss < 8; ++ss) {
    out[(size_t)(r0 + ss) * TDIN + tid]       = p[ss][0];
    out[(size_t)(r0 + ss) * TDIN + tid + 256] = p[ss][1];
    out[(size_t)(r0 + ss) * TDIN + tid + 512] = p[ss][2];
  }
}

// ================= host launcher =================
extern "C" void kernel_launch(void* const* d_in, const int* in_sizes, int n_in,
                              void* d_out, int out_size, void* d_ws, size_t ws_size,
                              hipStream_t stream) {
  (void)in_sizes; (void)n_in; (void)out_size; (void)ws_size;
  const float* x           = (const float*)d_in[0];
  const float* slot_memory = (const float*)d_in[1];
  const float* ln_w        = (const float*)d_in[2];
  const float* ln_b        = (const float*)d_in[3];
  const float* w_in        = (const float*)d_in[4];
  const float* w_q         = (const float*)d_in[5];
  const float* w_k         = (const float*)d_in[6];
  const float* w_v         = (const float*)d_in[7];
  const float* w_gate      = (const float*)d_in[8];
  const float* b_gate      = (const float*)d_in[9];
  const float* halt_w1     = (const float*)d_in[10];
  const float* halt_b1     = (const float*)d_in[11];
  const float* halt_w2     = (const float*)d_in[12];
  const float* halt_b2     = (const float*)d_in[13];
  const float* w_out       = (const float*)d_in[14];
  const float* dn_wk       = (const float*)d_in[15];
  const float* dn_wv       = (const float*)d_in[16];
  const float* dn_wb       = (const float*)d_in[17];
  const float* dn_bb       = (const float*)d_in[18];
  const float* dn_lam      = (const float*)d_in[19];
  const float* dn_wo       = (const float*)d_in[20];
  float* ws  = (float*)d_ws;
  float* out = (float*)d_out;

  k0_prep<<<dim3(64), dim3(256), 0, stream>>>(w_q, w_k, dn_lam, dn_wo, ws);
  k1_qk<<<dim3(256), dim3(256), 0, stream>>>(x, ln_w, ln_b, w_in, ws);
  k2_main<<<dim3(TB), dim3(1024), 0, stream>>>(slot_memory, w_v, w_gate, b_gate,
                                               halt_w1, halt_b1, halt_w2, halt_b2,
                                               dn_wk, dn_wv, dn_wb, dn_bb, dn_wo,
                                               ws, out);
  k3_out<<<dim3(128), dim3(256), 0, stream>>>(w_out, ws, out);
}

// Round 2
// 45241.943 us; speedup vs baseline: 1.0253x; 1.0253x over previous
//
#include <hip/hip_runtime.h>
#include <cstdint>

// ---------------- problem dims ----------------
#define TB 8
#define TS 128
#define TDIN 768
#define TN 64
#define TD 128
#define TH 4
#define TMAXT 8

// ---------------- workspace layout (float offsets) ----------------
#define WS_WLAM 0                         // 128*128 : diag(lam) @ dn_wo
#define WS_M    16384                     // 128*128 : M = w_q @ w_k^T  (qk = xp @ M)
#define WS_QK   32768                     // B*S*128 : per-(b,s) query-key vector
#define WS_ACC  (32768 + 131072)          // B*S*128 : per-step acc (consumed by epilogue)
#define WS_HALT (163840 + 131072)         // u64[MAXT*8]: packed {stamp<<32 | halt bits}

__device__ __forceinline__ float wsum64(float v) {
  v += __shfl_xor(v, 1);  v += __shfl_xor(v, 2);  v += __shfl_xor(v, 4);
  v += __shfl_xor(v, 8);  v += __shfl_xor(v, 16); v += __shfl_xor(v, 32);
  return v;
}
__device__ __forceinline__ float wmax64(float v) {
  v = fmaxf(v, __shfl_xor(v, 1));  v = fmaxf(v, __shfl_xor(v, 2));
  v = fmaxf(v, __shfl_xor(v, 4));  v = fmaxf(v, __shfl_xor(v, 8));
  v = fmaxf(v, __shfl_xor(v, 16)); v = fmaxf(v, __shfl_xor(v, 32));
  return v;
}

// ================= kernel 0: Wlam and M = w_q @ w_k^T =================
__global__ __launch_bounds__(256) void k0_prep(const float* __restrict__ w_q,
                                               const float* __restrict__ w_k,
                                               const float* __restrict__ dn_lam,
                                               const float* __restrict__ dn_wo,
                                               float* __restrict__ ws) {
  const int bx = blockIdx.x, tid = threadIdx.x;
  if (bx < 32) {
    int i = bx * 512 + tid;
    ws[WS_WLAM + i] = dn_lam[i >> 7] * dn_wo[i];
    i += 256;
    ws[WS_WLAM + i] = dn_lam[i >> 7] * dn_wo[i];
  } else {
    __shared__ float part[2][128];
    const int r0 = (bx - 32) * 4;
    const int c = tid & 127, half = tid >> 7;
    for (int rr = 0; rr < 4; ++rr) {
      const int k = r0 + rr;
      const float* wq = w_q + k * TD + half * 64;
      const float* wk = w_k + c * TD + half * 64;
      float p = 0.f;
      #pragma unroll 8
      for (int d = 0; d < 64; ++d) p = fmaf(wq[d], wk[d], p);
      part[half][c] = p;
      __syncthreads();
      if (tid < 128) ws[WS_M + k * TD + tid] = part[0][tid] + part[1][tid];
      __syncthreads();
    }
  }
}

// ================= kernel 1: qk_all[b][s] = LN(x) @ w_in @ M =================
__global__ __launch_bounds__(256) void k1_qk(const float* __restrict__ x,
                                             const float* __restrict__ ln_w,
                                             const float* __restrict__ ln_b,
                                             const float* __restrict__ w_in,
                                             float* __restrict__ ws) {
  const int bx = blockIdx.x, tid = threadIdx.x;
  const int b = bx >> 5;             // 8 batches x 32 blocks
  const int s0 = (bx & 31) * 4;      // 4 seq positions per block
  const int wv = tid >> 6, lane = tid & 63;

  __shared__ float xn[4][TDIN];
  __shared__ float xp[4][TD];
  __shared__ float part[2][4][TD];
  __shared__ float red[4];

  for (int ss = 0; ss < 4; ++ss) {
    const float* xrow = x + ((size_t)(b * TS + s0 + ss)) * TDIN;
    float v0 = xrow[tid], v1 = xrow[tid + 256], v2 = xrow[tid + 512];
    float p = wsum64(v0 + v1 + v2);
    if (lane == 0) red[wv] = p;
    __syncthreads();
    const float mu = (red[0] + red[1] + red[2] + red[3]) * (1.f / 768.f);
    __syncthreads();
    const float d0 = v0 - mu, d1 = v1 - mu, d2 = v2 - mu;
    p = wsum64(d0 * d0 + d1 * d1 + d2 * d2);
    if (lane == 0) red[wv] = p;
    __syncthreads();
    const float var = (red[0] + red[1] + red[2] + red[3]) * (1.f / 768.f);
    const float rstd = 1.f / sqrtf(var + 1e-5f);
    xn[ss][tid]       = d0 * rstd * ln_w[tid]       + ln_b[tid];
    xn[ss][tid + 256] = d1 * rstd * ln_w[tid + 256] + ln_b[tid + 256];
    xn[ss][tid + 512] = d2 * rstd * ln_w[tid + 512] + ln_b[tid + 512];
    __syncthreads();
  }

  {
    const int d = tid & 127, j = tid >> 7;
    float a0 = 0.f, a1 = 0.f, a2 = 0.f, a3 = 0.f;
    const int kb = j * 384;
    #pragma unroll 4
    for (int k = 0; k < 384; ++k) {
      const float w = w_in[(kb + k) * TD + d];
      a0 = fmaf(xn[0][kb + k], w, a0);
      a1 = fmaf(xn[1][kb + k], w, a1);
      a2 = fmaf(xn[2][kb + k], w, a2);
      a3 = fmaf(xn[3][kb + k], w, a3);
    }
    part[j][0][d] = a0; part[j][1][d] = a1; part[j][2][d] = a2; part[j][3][d] = a3;
  }
  __syncthreads();
  if (tid < 128) {
    #pragma unroll
    for (int ss = 0; ss < 4; ++ss) xp[ss][tid] = part[0][ss][tid] + part[1][ss][tid];
  }
  __syncthreads();
  {
    const int c = tid & 127, j = tid >> 7;
    float a0 = 0.f, a1 = 0.f, a2 = 0.f, a3 = 0.f;
    const float* Mp = ws + WS_M;
    const int kb = j * 64;
    #pragma unroll 4
    for (int k = 0; k < 64; ++k) {
      const float m = Mp[(kb + k) * TD + c];
      a0 = fmaf(xp[0][kb + k], m, a0);
      a1 = fmaf(xp[1][kb + k], m, a1);
      a2 = fmaf(xp[2][kb + k], m, a2);
      a3 = fmaf(xp[3][kb + k], m, a3);
    }
    part[j][0][c] = a0; part[j][1][c] = a1; part[j][2][c] = a2; part[j][3][c] = a3;
  }
  __syncthreads();
  if (tid < 128) {
    #pragma unroll
    for (int ss = 0; ss < 4; ++ss)
      ws[WS_QK + (size_t)(b * TS + s0 + ss) * TD + tid] = part[0][ss][tid] + part[1][ss][tid];
  }
}

// ---------------- k2 helpers: per-wave column tiles ----------------
// col split: w0:2@126 (after chain), w1:19@0, w2:19@19, w3:19@38, w4:15@57,
//            w5:18@72, w6:18@90, w7:18@108   (SIMD-pairing balanced)

template<int C0, int NC>
__device__ __forceinline__ void gemm_cols(const float* __restrict__ Wlam,
                                          const float (*S)[129], int l, float* G) {
  #pragma unroll
  for (int j = 0; j < NC; ++j) G[j] = 0.f;
  #pragma unroll 4
  for (int k = 0; k < 128; ++k) {
    const float a = S[l][k];                    // bank (l+k)%32 -> conflict-free
    const float* wr = Wlam + k * TD + C0;       // wave-uniform (broadcast)
    #pragma unroll
    for (int j = 0; j < NC; ++j) G[j] = fmaf(a, wr[j], G[j]);
  }
}

template<int C0, int NC>
__device__ __forceinline__ float score_cols(const float (*S)[129], int l,
                                            const float* sh_qk) {
  float sp = 0.f;
  #pragma unroll
  for (int j = 0; j < NC; ++j) sp = fmaf(S[l][C0 + j], sh_qk[C0 + j], sp);
  return sp;
}

template<int C0, int NC>
__device__ __forceinline__ float commit_cols(float (*S)[129], int l, const float* G,
                                             float g, float kh0, float kh1, float kh2, float kh3,
                                             const float (*sh_vo)[TD], const float (*sh_ko)[TD],
                                             const float* sh_qk) {
  float sp = 0.f;
  #pragma unroll
  for (int j = 0; j < NC; ++j) {
    const int c = C0 + j;
    float u = G[j];
    u += sh_vo[0][c] - kh0 * sh_ko[0][c];
    u += sh_vo[1][c] - kh1 * sh_ko[1][c];
    u += sh_vo[2][c] - kh2 * sh_ko[2][c];
    u += sh_vo[3][c] - kh3 * sh_ko[3][c];
    const float ns = (1.f - g) * S[l][c] + g * u;
    S[l][c] = ns;
    sp = fmaf(ns, sh_qk[c], sp);
  }
  return sp;
}

template<int C0, int NC>
__device__ __forceinline__ void store_cols(const float (*S)[129], int l,
                                           float* __restrict__ dst) {
  #pragma unroll
  for (int j = 0; j < NC; ++j) dst[l * TD + C0 + j] = S[l][C0 + j];
}

// ================= kernel 2: the recurrence (8 blocks, 512 thr, 1 per batch) =================
__global__ __launch_bounds__(512) void k2_main(
    const float* __restrict__ slot_memory,
    const float* __restrict__ w_v,     const float* __restrict__ w_gate,  const float* __restrict__ b_gate,
    const float* __restrict__ halt_w1, const float* __restrict__ halt_b1,
    const float* __restrict__ halt_w2, const float* __restrict__ halt_b2,
    const float* __restrict__ dn_wk,   const float* __restrict__ dn_wv,
    const float* __restrict__ dn_wb,   const float* __restrict__ dn_bb,
    const float* __restrict__ dn_wo,
    float* __restrict__ ws, float* __restrict__ out) {
  const int tid = threadIdx.x;
  const int b = blockIdx.x;
  const int l = tid & 63, wv = tid >> 6;

  __shared__ float S[TN][129];               // slots, pad 129 -> conflict-free b32
  __shared__ float sh_scorepart[8][TN];
  __shared__ float sh_qk[TD];
  __shared__ float sh_attn[TN];
  __shared__ float sh_rs[TD];
  __shared__ float sh_ro[TD];
  __shared__ float sh_gate[TN];
  __shared__ float sh_kn[TD];
  __shared__ float sh_v[TD];
  __shared__ float sh_beta[TH];
  __shared__ float sh_vo[TH][TD];
  __shared__ float sh_ko[TH][TD];
  __shared__ float sh_kh[TH][TN];            // [h][n] -> conflict-free reads at commit
  __shared__ int   sh_break;

  unsigned long long* hslots = (unsigned long long*)(ws + WS_HALT);
  const float* Wlam = ws + WS_WLAM;

  for (int i = tid; i < TN * TD; i += 512)
    S[i >> 7][i & 127] = slot_memory[i];

  float acc0 = 0.f, acc1 = 0.f, rem = 1.f, hl = 0.f;   // wave0 state

  for (int s = 0; s < TS; ++s) {
    if (tid < TD) sh_qk[tid] = ws[WS_QK + (size_t)(b * TS + s) * TD + tid];
    if (wv == 0) { acc0 = 0.f; acc1 = 0.f; rem = 1.f; }
    __syncthreads();
    // step-start score partials (fresh qk, current slots)
    {
      float sp;
      switch (wv) {
        case 0: sp = score_cols<126, 2>(S, l, sh_qk); break;
        case 1: sp = score_cols<0, 19>(S, l, sh_qk); break;
        case 2: sp = score_cols<19, 19>(S, l, sh_qk); break;
        case 3: sp = score_cols<38, 19>(S, l, sh_qk); break;
        case 4: sp = score_cols<57, 15>(S, l, sh_qk); break;
        case 5: sp = score_cols<72, 18>(S, l, sh_qk); break;
        case 6: sp = score_cols<90, 18>(S, l, sh_qk); break;
        default: sp = score_cols<108, 18>(S, l, sh_qk); break;
      }
      sh_scorepart[wv][l] = sp;
    }
    __syncthreads();

    for (int t = 0; t < TMAXT; ++t) {
      float G[19];
      float ro0 = 0.f, ro1 = 0.f;
      if (wv == 0) {
        // ---------- serial chain, entirely intra-wave ----------
        // softmax over slots
        float sc = sh_scorepart[0][l] + sh_scorepart[1][l] + sh_scorepart[2][l] + sh_scorepart[3][l]
                 + sh_scorepart[4][l] + sh_scorepart[5][l] + sh_scorepart[6][l] + sh_scorepart[7][l];
        const float y = sc * 0.08838834764831845f;     // 1/sqrt(128)
        const float mx = wmax64(y);
        const float e = expf(y - mx);
        const float se = wsum64(e);
        sh_attn[l] = e / se;
        // rs = attn @ slots   (d-pair: l, l+64)
        float r0 = 0.f, r1 = 0.f;
        #pragma unroll 8
        for (int n = 0; n < TN; ++n) {
          const float a = sh_attn[n];
          r0 = fmaf(a, S[n][l], r0);
          r1 = fmaf(a, S[n][l + 64], r1);
        }
        sh_rs[l] = r0; sh_rs[l + 64] = r1;
        // ro = rs @ w_v
        float o0 = 0.f, o1 = 0.f;
        #pragma unroll 4
        for (int k = 0; k < TD; ++k) {
          const float rk = sh_rs[k];
          o0 = fmaf(rk, w_v[k * TD + l], o0);
          o1 = fmaf(rk, w_v[k * TD + l + 64], o1);
        }
        sh_ro[l] = o0; sh_ro[l + 64] = o1;
        ro0 = o0; ro1 = o1;
        // halt (publish ASAP)
        float t1 = 0.f;
        #pragma unroll 4
        for (int k = 0; k < TD; ++k) t1 = fmaf(sh_ro[k], halt_w1[k * 64 + l], t1);
        t1 = fmaxf(t1 + halt_b1[l], 0.f);
        const float z = wsum64(t1 * halt_w2[l]);
        hl = 1.f / (1.f + expf(-(z + halt_b2[0])));
        if (l == 0 && t >= 1 && t <= 6) {
          const unsigned long long pv =
              ((unsigned long long)(unsigned)(s * 8 + t) << 32) | (unsigned long long)__float_as_uint(hl);
          __hip_atomic_store(&hslots[t * 8 + b], pv, __ATOMIC_RELAXED, __HIP_MEMORY_SCOPE_AGENT);
        }
        // gate
        float gg = 0.f;
        #pragma unroll 4
        for (int k = 0; k < TD; ++k) gg = fmaf(sh_ro[k], w_gate[k * 64 + l], gg);
        sh_gate[l] = 1.f / (1.f + expf(-(gg + b_gate[l])));
        // k raw + per-head normalize (heads: d0=l -> l>>5; d1=l+64 -> 2+(l>>5))
        float ka = 0.f, kb = 0.f;
        #pragma unroll 4
        for (int k = 0; k < TD; ++k) {
          const float rk = sh_ro[k];
          ka = fmaf(rk, dn_wk[k * TD + l], ka);
          kb = fmaf(rk, dn_wk[k * TD + l + 64], kb);
        }
        float sa = ka * ka, sb = kb * kb;
        #pragma unroll
        for (int m = 1; m <= 16; m <<= 1) { sa += __shfl_xor(sa, m); sb += __shfl_xor(sb, m); }
        sh_kn[l] = ka / (sqrtf(sa) + 1e-6f);
        sh_kn[l + 64] = kb / (sqrtf(sb) + 1e-6f);
        // v
        float va = 0.f, vb = 0.f;
        #pragma unroll 4
        for (int k = 0; k < TD; ++k) {
          const float rk = sh_ro[k];
          va = fmaf(rk, dn_wv[k * TD + l], va);
          vb = fmaf(rk, dn_wv[k * TD + l + 64], vb);
        }
        sh_v[l] = va; sh_v[l + 64] = vb;
        // beta (h = l&3, 16 k-strips of 8)
        {
          const int h = l & 3, k0 = (l >> 2) * 8;
          float bp = 0.f;
          #pragma unroll
          for (int i = 0; i < 8; ++i) bp = fmaf(sh_ro[k0 + i], dn_wb[(k0 + i) * TH + h], bp);
          bp += __shfl_xor(bp, 4); bp += __shfl_xor(bp, 8);
          bp += __shfl_xor(bp, 16); bp += __shfl_xor(bp, 32);
          const float be = 2.f / (1.f + expf(-(bp + dn_bb[h])));
          if (l < 4) sh_beta[l] = be;
        }
        // vo/ko per head (shared wo loads)
        #pragma unroll
        for (int h = 0; h < TH; ++h) {
          float a0 = 0.f, a1 = 0.f, c0 = 0.f, c1 = 0.f;
          #pragma unroll 4
          for (int i = 0; i < 32; ++i) {
            const int k = h * 32 + i;
            const float w0 = dn_wo[k * TD + l], w1 = dn_wo[k * TD + l + 64];
            const float vvv = sh_v[k], kkk = sh_kn[k];
            a0 = fmaf(vvv, w0, a0); a1 = fmaf(vvv, w1, a1);
            c0 = fmaf(kkk, w0, c0); c1 = fmaf(kkk, w1, c1);
          }
          const float bh = sh_beta[h];
          sh_vo[h][l] = bh * a0; sh_vo[h][l + 64] = bh * a1;
          sh_ko[h][l] = bh * c0; sh_ko[h][l + 64] = bh * c1;
        }
        // kh[n][h] (lane = n)
        {
          float kh0 = 0.f, kh1 = 0.f, kh2 = 0.f, kh3 = 0.f;
          #pragma unroll 4
          for (int i = 0; i < 32; ++i) {
            kh0 = fmaf(sh_kn[i], S[l][i], kh0);
            kh1 = fmaf(sh_kn[32 + i], S[l][32 + i], kh1);
            kh2 = fmaf(sh_kn[64 + i], S[l][64 + i], kh2);
            kh3 = fmaf(sh_kn[96 + i], S[l][96 + i], kh3);
          }
          sh_kh[0][l] = kh0; sh_kh[1][l] = kh1; sh_kh[2][l] = kh2; sh_kh[3][l] = kh3;
        }
        // wave0's own 2 GEMM cols
        gemm_cols<126, 2>(Wlam, S, l, G);
      } else {
        switch (wv) {
          case 1: gemm_cols<0, 19>(Wlam, S, l, G); break;
          case 2: gemm_cols<19, 19>(Wlam, S, l, G); break;
          case 3: gemm_cols<38, 19>(Wlam, S, l, G); break;
          case 4: gemm_cols<57, 15>(Wlam, S, l, G); break;
          case 5: gemm_cols<72, 18>(Wlam, S, l, G); break;
          case 6: gemm_cols<90, 18>(Wlam, S, l, G); break;
          default: gemm_cols<108, 18>(Wlam, S, l, G); break;
        }
        if (wv == 1) {
          // halt-mean poll, off the critical path (published ~1 tick ago)
          if (l < 8) {
            if (t >= 2) {
              const unsigned want = (unsigned)(s * 8 + t - 1);
              unsigned long long vv_;
              do {
                vv_ = __hip_atomic_load(&hslots[(t - 1) * 8 + l], __ATOMIC_RELAXED, __HIP_MEMORY_SCOPE_AGENT);
              } while ((unsigned)(vv_ >> 32) != want);
              float hv = __uint_as_float((unsigned)vv_);
              hv += __shfl_xor(hv, 1); hv += __shfl_xor(hv, 2); hv += __shfl_xor(hv, 4);
              if (l == 0) sh_break = (hv * 0.125f > 0.5f) ? 1 : 0;
            } else if (l == 0) {
              sh_break = 0;
            }
          }
        }
      }
      __syncthreads();   // B: chain products + G + break flag ready
      const int brk = sh_break;
      if (!brk) {
        const float g = sh_gate[l];
        const float kh0 = sh_kh[0][l], kh1 = sh_kh[1][l], kh2 = sh_kh[2][l], kh3 = sh_kh[3][l];
        float sp;
        switch (wv) {
          case 0: sp = commit_cols<126, 2>(S, l, G, g, kh0, kh1, kh2, kh3, sh_vo, sh_ko, sh_qk); break;
          case 1: sp = commit_cols<0, 19>(S, l, G, g, kh0, kh1, kh2, kh3, sh_vo, sh_ko, sh_qk); break;
          case 2: sp = commit_cols<19, 19>(S, l, G, g, kh0, kh1, kh2, kh3, sh_vo, sh_ko, sh_qk); break;
          case 3: sp = commit_cols<38, 19>(S, l, G, g, kh0, kh1, kh2, kh3, sh_vo, sh_ko, sh_qk); break;
          case 4: sp = commit_cols<57, 15>(S, l, G, g, kh0, kh1, kh2, kh3, sh_vo, sh_ko, sh_qk); break;
          case 5: sp = commit_cols<72, 18>(S, l, G, g, kh0, kh1, kh2, kh3, sh_vo, sh_ko, sh_qk); break;
          case 6: sp = commit_cols<90, 18>(S, l, G, g, kh0, kh1, kh2, kh3, sh_vo, sh_ko, sh_qk); break;
          default: sp = commit_cols<108, 18>(S, l, G, g, kh0, kh1, kh2, kh3, sh_vo, sh_ko, sh_qk); break;
        }
        sh_scorepart[wv][l] = sp;
        if (wv == 0) {
          acc0 += rem * ro0; acc1 += rem * ro1;
          if (t < TMAXT - 1) rem *= (1.f - hl);
        }
      }
      __syncthreads();   // A: commit visible before next tick / step
      if (brk) break;
    }  // ticks

    if (wv == 0) {
      ws[WS_ACC + (size_t)(b * TS + s) * TD + l] = acc0;
      ws[WS_ACC + (size_t)(b * TS + s) * TD + l + 64] = acc1;
    }
  }  // steps

  // slots_final -> out
  {
    float* dst = out + (size_t)TB * TS * TDIN + (size_t)b * TN * TD;
    switch (wv) {
      case 0: store_cols<126, 2>(S, l, dst); break;
      case 1: store_cols<0, 19>(S, l, dst); break;
      case 2: store_cols<19, 19>(S, l, dst); break;
      case 3: store_cols<38, 19>(S, l, dst); break;
      case 4: store_cols<57, 15>(S, l, dst); break;
      case 5: store_cols<72, 18>(S, l, dst); break;
      case 6: store_cols<90, 18>(S, l, dst); break;
      default: store_cols<108, 18>(S, l, dst); break;
    }
  }
}

// ================= kernel 3: outs = acc_all @ w_out =================
__global__ __launch_bounds__(256) void k3_out(const float* __restrict__ w_out,
                                              const float* __restrict__ ws,
                                              float* __restrict__ out) {
  const int bx = blockIdx.x, tid = threadIdx.x;
  const int r0 = bx * 8;
  __shared__ float a8[8][TD];
  for (int i = tid; i < 8 * TD; i += 256)
    a8[i >> 7][i & 127] = ws[WS_ACC + (size_t)r0 * TD + i];
  __syncthreads();
  float p[8][3];
  #pragma unroll
  for (int ss = 0; ss < 8; ++ss) { p[ss][0] = 0.f; p[ss][1] = 0.f; p[ss][2] = 0.f; }
  #pragma unroll 2
  for (int d = 0; d < TD; ++d) {
    const float w0 = w_out[d * TDIN + tid];
    const float w1 = w_out[d * TDIN + tid + 256];
    const float w2 = w_out[d * TDIN + tid + 512];
    #pragma unroll
    for (int ss = 0; ss < 8; ++ss) {
      const float a = a8[ss][d];
      p[ss][0] = fmaf(a, w0, p[ss][0]);
      p[ss][1] = fmaf(a, w1, p[ss][1]);
      p[ss][2] = fmaf(a, w2, p[ss][2]);
    }
  }
  #pragma unroll
  for (int ss = 0; ss < 8; ++ss) {
    out[(size_t)(r0 + ss) * TDIN + tid]       = p[ss][0];
    out[(size_t)(r0 + ss) * TDIN + tid + 256] = p[ss][1];
    out[(size_t)(r0 + ss) * TDIN + tid + 512] = p[ss][2];
  }
}

// ================= host launcher =================
extern "C" void kernel_launch(void* const* d_in, const int* in_sizes, int n_in,
                              void* d_out, int out_size, void* d_ws, size_t ws_size,
                              hipStream_t stream) {
  (void)in_sizes; (void)n_in; (void)out_size; (void)ws_size;
  const float* x           = (const float*)d_in[0];
  const float* slot_memory = (const float*)d_in[1];
  const float* ln_w        = (const float*)d_in[2];
  const float* ln_b        = (const float*)d_in[3];
  const float* w_in        = (const float*)d_in[4];
  const float* w_q         = (const float*)d_in[5];
  const float* w_k         = (const float*)d_in[6];
  const float* w_v         = (const float*)d_in[7];
  const float* w_gate      = (const float*)d_in[8];
  const float* b_gate      = (const float*)d_in[9];
  const float* halt_w1     = (const float*)d_in[10];
  const float* halt_b1     = (const float*)d_in[11];
  const float* halt_w2     = (const float*)d_in[12];
  const float* halt_b2     = (const float*)d_in[13];
  const float* w_out       = (const float*)d_in[14];
  const float* dn_wk       = (const float*)d_in[15];
  const float* dn_wv       = (const float*)d_in[16];
  const float* dn_wb       = (const float*)d_in[17];
  const float* dn_bb       = (const float*)d_in[18];
  const float* dn_lam      = (const float*)d_in[19];
  const float* dn_wo       = (const float*)d_in[20];
  float* ws  = (float*)d_ws;
  float* out = (float*)d_out;

  k0_prep<<<dim3(64), dim3(256), 0, stream>>>(w_q, w_k, dn_lam, dn_wo, ws);
  k1_qk<<<dim3(256), dim3(256), 0, stream>>>(x, ln_w, ln_b, w_in, ws);
  k2_main<<<dim3(TB), dim3(512), 0, stream>>>(slot_memory, w_v, w_gate, b_gate,
                                              halt_w1, halt_b1, halt_w2, halt_b2,
                                              dn_wk, dn_wv, dn_wb, dn_bb, dn_wo,
                                              ws, out);
  k3_out<<<dim3(128), dim3(256), 0, stream>>>(w_out, ws, out);
}